// Round 7
// baseline (94.493 us; speedup 1.0000x reference)
//
#include <hip/hip_runtime.h>

// VQ-VAE vector quantizer, MI355X. Single fused kernel + tiny init.
//  Phase A: z -> Ag granule-planar bf16 + znorm ; emb -> Bg + enorm ; emb -> emb_t
//  [device barrier]
//  Phase B: 256x256x256 bf16 MFMA tile (XCD-swizzled) -> planar part[np][row]
//  [device barrier]
//  Phase C: min over 4 planes -> idx -> LDS-staged gather -> out ; fixed-point loss
// grid = 256 blocks x 512 thr, 136KB LDS => 1 block/CU, all co-resident (spin barrier safe)
// z: [16,256,32,32] f32, emb_w: [1024,256] f32
// out: z_q f32 (4194304) ++ loss scalar (1 float)

#define K_CODES 1024
#define D_DIM   256
#define N_VEC   16384
#define ZQ_SIZE 4194304

typedef unsigned short ushort_t;
typedef unsigned long long u64;
typedef short bf16x8 __attribute__((ext_vector_type(8)));
typedef float f32x16 __attribute__((ext_vector_type(16)));

struct Ctrl { unsigned c1, c2, done, pad; u64 lsum; };

__device__ __forceinline__ ushort_t f2bf(float x) {
    unsigned int b = __float_as_uint(x);
    b += 0x7fffu + ((b >> 16) & 1u);   // RNE
    return (ushort_t)(b >> 16);
}

__device__ __forceinline__ void gload_lds16(const void* g, void* l) {
    __builtin_amdgcn_global_load_lds(
        (const __attribute__((address_space(1))) void*)g,
        (__attribute__((address_space(3))) void*)l, 16, 0, 0);
}

__device__ __forceinline__ void dev_barrier(unsigned* cnt, unsigned target) {
    __syncthreads();
    if (threadIdx.x == 0) {
        __threadfence();                    // release: agent-scope (L2 writeback)
        atomicAdd(cnt, 1u);
        while (atomicAdd(cnt, 0u) < target) __builtin_amdgcn_s_sleep(4);
        __threadfence();                    // acquire: invalidate stale lines
    }
    __syncthreads();
}

__global__ void vq_init(Ctrl* c) {
    if (threadIdx.x == 0) { c->c1 = 0u; c->c2 = 0u; c->done = 0u; c->lsum = 0ull; }
}

__global__ __launch_bounds__(512, 2) void vq_fused(
        const float* __restrict__ z, const float* __restrict__ emb,
        ushort_t* __restrict__ Ag, ushort_t* __restrict__ Bg,
        float* __restrict__ emb_t, float* __restrict__ enorm,
        float* __restrict__ znorm, u64* __restrict__ part,
        float* __restrict__ out, float* __restrict__ loss, Ctrl* __restrict__ ctrl) {
    __shared__ __align__(16) char smem[139264];   // phase-aliased
    const int bid = blockIdx.x;
    const int tid = threadIdx.x;

    //================ PHASE A: prep ================
    {
        float* zt  = (float*)smem;              // [128][68] f32 (34816 B)
        float* znp = (float*)(smem + 34816);    // [8][64]   (2048 B)
        float* tp  = (float*)(smem + 36864);    // [32][33]  (4224 B)

        // z -> Ag for rows [bid*64, bid*64+64), all 256 d (2 passes of 128 d)
        const int b = bid >> 4, q = bid & 15;
        const int n0 = bid * 64;
        const float* zb = z + (size_t)b * (256 * 1024) + q * 64;
        const int hw = tid & 63, ds = tid >> 6;          // ds in [0,8)
        float zn = 0.f;
#pragma unroll
        for (int p = 0; p < 2; ++p) {
#pragma unroll
            for (int i = 0; i < 4; ++i) {
                const int dl = i * 32 + (tid >> 4);       // [0,128)
                const int c  = (tid & 15) * 4;
                *(float4*)(zt + dl * 68 + c) =
                    *(const float4*)(zb + (size_t)(p * 128 + dl) * 1024 + c);
            }
            __syncthreads();
#pragma unroll
            for (int i2 = 0; i2 < 2; ++i2) {
                const int dl = ds * 16 + i2 * 8;          // local d base
                const int g  = (p * 128 + dl) >> 3;       // granule plane
                float v[8]; ushort_t o[8];
#pragma unroll
                for (int j = 0; j < 8; ++j) {
                    v[j] = zt[(dl + j) * 68 + hw];        // 2-way alias: free
                    zn += v[j] * v[j];
                    o[j] = f2bf(v[j]);
                }
                *(bf16x8*)(Ag + ((size_t)g * N_VEC + n0 + hw) * 8) = *(bf16x8*)o; // 1KB/wave
            }
            __syncthreads();
        }
        znp[ds * 64 + hw] = zn;

        // emb -> Bg (threads 256..383: 128 granules for this block)
        if (tid >= 256 && tid < 384) {
            const int gi = bid * 128 + (tid - 256);
            const int g = gi & 31, k = gi >> 5;
            const float4 v0 = *(const float4*)(emb + k * D_DIM + g * 8);
            const float4 v1 = *(const float4*)(emb + k * D_DIM + g * 8 + 4);
            ushort_t o[8];
            o[0] = f2bf(v0.x); o[1] = f2bf(v0.y); o[2] = f2bf(v0.z); o[3] = f2bf(v0.w);
            o[4] = f2bf(v1.x); o[5] = f2bf(v1.y); o[6] = f2bf(v1.z); o[7] = f2bf(v1.w);
            *(bf16x8*)(Bg + ((size_t)g * K_CODES + k) * 8) = *(bf16x8*)o;
            float s = v0.x * v0.x + v0.y * v0.y + v0.z * v0.z + v0.w * v0.w
                    + v1.x * v1.x + v1.y * v1.y + v1.z * v1.z + v1.w * v1.w;
#pragma unroll
            for (int off = 16; off >= 1; off >>= 1) s += __shfl_xor(s, off);
            if ((tid & 31) == 0) enorm[k] = s;
        }
        // emb -> emb_t: one 32x32 tile per block (threads 0..255 load)
        const int kt = bid & 31, dt = bid >> 5;
        if (tid < 256) {
            const int c = tid & 31, r4 = tid >> 5;
#pragma unroll
            for (int p = 0; p < 4; ++p) {
                int r = r4 * 4 + p;
                tp[r * 33 + c] = emb[(kt * 32 + r) * D_DIM + dt * 32 + c];
            }
        }
        __syncthreads();
        if (tid < 64)
            znorm[n0 + tid] = znp[tid] + znp[64 + tid] + znp[128 + tid] + znp[192 + tid]
                            + znp[256 + tid] + znp[320 + tid] + znp[384 + tid] + znp[448 + tid];
        if (tid < 256) {
            const int c = tid & 31, r4 = tid >> 5;
#pragma unroll
            for (int p = 0; p < 4; ++p) {
                int r = r4 * 4 + p;
                emb_t[(dt * 32 + r) * K_CODES + kt * 32 + c] = tp[c * 33 + r];
            }
        }
    }

    dev_barrier(&ctrl->c1, 256u);

    //================ PHASE B: MFMA argmin ================
    {
        ushort_t* As0 = (ushort_t*)smem;                  // 2 x 32 KB
        ushort_t* Bs0 = (ushort_t*)(smem + 65536);        // 2 x 32 KB
        u64 (*pmin_lds)[4] = (u64 (*)[4])(smem + 131072); // 8 KB

        const int w = tid >> 6, l = tid & 63;
        const int wm = w >> 2, wn = w & 3;
        const int lane31 = l & 31, hi = l >> 5;
        // XCD swizzle: give XCD x m-tiles [8x,8x+8) so all 4 n-panels share one L2
        const int swz = (bid & 7) * 32 + (bid >> 3);
        const int mt = swz >> 2, np = swz & 3;
        const int m0 = mt * 256, n0 = np * 256;

        f32x16 acc[4][2];
#pragma unroll
        for (int mi = 0; mi < 4; ++mi)
#pragma unroll
            for (int ni = 0; ni < 2; ++ni)
#pragma unroll
                for (int r = 0; r < 16; ++r) acc[mi][ni][r] = 0.f;

        auto stage = [&](int buf, int t) {
#pragma unroll
            for (int qq = 0; qq < 4; ++qq) {
                int g = qq * 512 + tid;                   // [0,2048)
                int cg = g >> 8, r = g & 255;
                gload_lds16(Ag + ((size_t)(t * 8 + cg) * N_VEC  + m0 + r) * 8,
                            As0 + (size_t)buf * 16384 + (size_t)g * 8);
                gload_lds16(Bg + ((size_t)(t * 8 + cg) * K_CODES + n0 + r) * 8,
                            Bs0 + (size_t)buf * 16384 + (size_t)g * 8);
            }
        };
        auto compute = [&](int buf) {
#pragma unroll
            for (int ks = 0; ks < 4; ++ks) {
                const int cgr = ks * 2 + hi;
                bf16x8 a[4], bb[2];
#pragma unroll
                for (int mi = 0; mi < 4; ++mi)
                    a[mi] = *(const bf16x8*)(As0 + (size_t)buf * 16384 +
                             ((size_t)cgr * 256 + wm * 128 + mi * 32 + lane31) * 8);
#pragma unroll
                for (int ni = 0; ni < 2; ++ni)
                    bb[ni] = *(const bf16x8*)(Bs0 + (size_t)buf * 16384 +
                              ((size_t)cgr * 256 + wn * 64 + ni * 32 + lane31) * 8);
#pragma unroll
                for (int mi = 0; mi < 4; ++mi)
#pragma unroll
                    for (int ni = 0; ni < 2; ++ni)
                        acc[mi][ni] = __builtin_amdgcn_mfma_f32_32x32x16_bf16(
                            a[mi], bb[ni], acc[mi][ni], 0, 0, 0);
            }
        };

        stage(0, 0);
        __syncthreads();
        for (int t = 0; t < 4; ++t) {
            if (t < 3) stage((t + 1) & 1, t + 1);
            compute(t & 1);
            __syncthreads();
        }

        float en[2]; unsigned int kg[2];
#pragma unroll
        for (int ni = 0; ni < 2; ++ni) {
            int col = n0 + wn * 64 + ni * 32 + lane31;
            en[ni] = enorm[col];
            kg[ni] = (unsigned int)col;
        }
#pragma unroll
        for (int mi = 0; mi < 4; ++mi) {
#pragma unroll
            for (int reg = 0; reg < 16; ++reg) {
                u64 p = ~0ull;
#pragma unroll
                for (int ni = 0; ni < 2; ++ni) {
                    float sc = en[ni] - 2.0f * acc[mi][ni][reg];
                    unsigned int bb2 = __float_as_uint(sc);
                    unsigned int u = bb2 ^ (unsigned int)(((int)bb2 >> 31) | 0x80000000);
                    u64 pk = ((u64)u << 32) | kg[ni];
                    if (pk < p) p = pk;
                }
#pragma unroll
                for (int off = 16; off >= 1; off >>= 1) {
                    u64 qv = __shfl_xor(p, off);
                    if (qv < p) p = qv;
                }
                if (lane31 == 0) {
                    int rloc = wm * 128 + mi * 32 + (reg & 3) + 8 * (reg >> 2) + 4 * hi;
                    pmin_lds[rloc][wn] = p;
                }
            }
        }
        __syncthreads();
        if (tid < 256) {
            u64 a = pmin_lds[tid][0], b2 = pmin_lds[tid][1];
            u64 c = pmin_lds[tid][2], d = pmin_lds[tid][3];
            u64 m = a < b2 ? a : b2;
            u64 m2 = c < d ? c : d;
            if (m2 < m) m = m2;
            part[(size_t)np * N_VEC + m0 + tid] = m;
        }
    }

    dev_barrier(&ctrl->c2, 256u);

    //================ PHASE C: gather + loss ================
    {
        float* et = (float*)smem;                   // 64 KB: emb_t rows [half*16, +16)
        const int b = bid >> 4, half = bid & 15;
        const int col = tid & 255, dgrp = tid >> 8; // dgrp in {0,1}
        const int n = b * 1024 + col * 4;

#pragma unroll
        for (int p = 0; p < 8; ++p) {
            int g = p * 512 + tid;                  // [0,4096) 16B granules
            gload_lds16(emb_t + (size_t)half * 16384 + g * 4, et + g * 4);
        }

        u64 m[4];
        {
            ulonglong2 p0 = *(const ulonglong2*)(part + n);
            ulonglong2 p1 = *(const ulonglong2*)(part + n + 2);
            m[0] = p0.x; m[1] = p0.y; m[2] = p1.x; m[3] = p1.y;
        }
#pragma unroll
        for (int np = 1; np < 4; ++np) {
            ulonglong2 p0 = *(const ulonglong2*)(part + (size_t)np * N_VEC + n);
            ulonglong2 p1 = *(const ulonglong2*)(part + (size_t)np * N_VEC + n + 2);
            if (p0.x < m[0]) m[0] = p0.x;
            if (p0.y < m[1]) m[1] = p0.y;
            if (p1.x < m[2]) m[2] = p1.x;
            if (p1.y < m[3]) m[3] = p1.y;
        }
        const unsigned i0 = (unsigned)(m[0] & 0xffffffffu), i1 = (unsigned)(m[1] & 0xffffffffu);
        const unsigned i2 = (unsigned)(m[2] & 0xffffffffu), i3 = (unsigned)(m[3] & 0xffffffffu);

        __syncthreads();   // et staged (barrier drains vmcnt)

#pragma unroll
        for (int d8 = 0; d8 < 8; ++d8) {
            const float* er = et + (dgrp * 8 + d8) * 1024;
            float4 qv;
            qv.x = er[i0]; qv.y = er[i1]; qv.z = er[i2]; qv.w = er[i3];
            *(float4*)(out + ((size_t)(b * 256 + half * 16 + dgrp * 8 + d8)) * 1024 + col * 4) = qv;
        }

        if (half == 0 && tid < 256) {   // 16 blocks x 4 waves accumulate loss
            const float4 zn4 = *(const float4*)(znorm + n);
            float lp = 0.f;
#pragma unroll
            for (int j = 0; j < 4; ++j) {
                unsigned int u = (unsigned int)(m[j] >> 32);
                unsigned int fb = (u & 0x80000000u) ? (u ^ 0x80000000u) : ~u;
                lp += __uint_as_float(fb);
            }
            lp += zn4.x + zn4.y + zn4.z + zn4.w;    // ||z||^2 + (||e||^2 - 2 z.e)
#pragma unroll
            for (int off = 32; off >= 1; off >>= 1) lp += __shfl_xor(lp, off);
            if ((tid & 63) == 0) {
                u64 fix = (u64)(long long)((double)lp * 1048576.0);
                atomicAdd(&ctrl->lsum, fix);
                __threadfence();
                unsigned old = atomicAdd(&ctrl->done, 1u);
                if (old == 63u) {
                    u64 tot = atomicAdd(&ctrl->lsum, 0ull);
                    loss[0] = (float)((double)tot * (1.25 / (1048576.0 * 4194304.0)));
                }
            }
        }
    }
}

extern "C" void kernel_launch(void* const* d_in, const int* in_sizes, int n_in,
                              void* d_out, int out_size, void* d_ws, size_t ws_size,
                              hipStream_t stream) {
    const float* z   = (const float*)d_in[0];
    const float* emb = (const float*)d_in[1];
    float* out  = (float*)d_out;
    float* loss = out + ZQ_SIZE;

    char* ws = (char*)d_ws;
    ushort_t* Ag  = (ushort_t*)(ws);              // 8,388,608 B  [32][16384] granules
    ushort_t* Bg  = (ushort_t*)(ws + 8388608);    //   524,288 B  [32][1024] granules
    float* emb_t  = (float*)(ws + 8912896);       // 1,048,576 B
    float* enorm  = (float*)(ws + 9961472);       //     4,096 B
    float* znorm  = (float*)(ws + 9965568);       //    65,536 B
    u64* part     = (u64*)(ws + 10031104);        //   524,288 B (4 planes x 16384)
    Ctrl* ctrl    = (Ctrl*)(ws + 10555392);       //        16 B

    vq_init<<<1, 64, 0, stream>>>(ctrl);
    vq_fused<<<256, 512, 0, stream>>>(z, emb, Ag, Bg, emb_t, enorm, znorm, part,
                                      out, loss, ctrl);
}

// Round 9
// 44.776 us; speedup vs baseline: 2.1104x; 2.1104x over previous
//
#include <hip/hip_runtime.h>

// VQ-VAE vector quantizer, MI355X. 2 kernels, no cross-block exchange.
//  K1 vq_prep : emb f32 -> Bg granule-planar bf16 [g][k][8] + enorm[k]; zero ctrl
//  K2 vq_main : per block = 64 rows x ALL 1024 codes x K=256.
//    prologue: z slice -> As bf16 LDS (granule-planar) + znorm (local, no global A)
//    K loop:   16 chunks (k=16), B dbuf-staged from Bg via global_load_lds
//    epilogue: per-row argmin (local!), idx -> LDS; gather emb rows -> et (local rows);
//              out[d][hw] = et[hw][d]; loss via fixed-point u64 atomicAdd
// z: [16,256,32,32] f32, emb_w: [1024,256] f32
// out: z_q f32 (4194304) ++ loss scalar (1 float)

#define K_CODES 1024
#define D_DIM   256
#define N_VEC   16384
#define ZQ_SIZE 4194304

typedef unsigned short ushort_t;
typedef unsigned long long u64;
typedef short bf16x8 __attribute__((ext_vector_type(8)));
typedef float f32x16 __attribute__((ext_vector_type(16)));

struct Ctrl { unsigned done; unsigned pad; u64 lsum; };

__device__ __forceinline__ ushort_t f2bf(float x) {
    unsigned int b = __float_as_uint(x);
    b += 0x7fffu + ((b >> 16) & 1u);   // RNE
    return (ushort_t)(b >> 16);
}

__device__ __forceinline__ void gload_lds16(const void* g, void* l) {
    __builtin_amdgcn_global_load_lds(
        (const __attribute__((address_space(1))) void*)g,
        (__attribute__((address_space(3))) void*)l, 16, 0, 0);
}

// ---------------- K1: emb -> Bg bf16 + enorm ; zero ctrl ----------------
__global__ __launch_bounds__(512) void vq_prep(
        const float* __restrict__ emb, ushort_t* __restrict__ Bg,
        float* __restrict__ enorm, Ctrl* __restrict__ ctrl) {
    const int gi = blockIdx.x * 512 + threadIdx.x;   // [0, 32768)
    const int k = gi >> 5, g = gi & 31;
    const float4 v0 = *(const float4*)(emb + k * D_DIM + g * 8);
    const float4 v1 = *(const float4*)(emb + k * D_DIM + g * 8 + 4);
    ushort_t o[8];
    o[0] = f2bf(v0.x); o[1] = f2bf(v0.y); o[2] = f2bf(v0.z); o[3] = f2bf(v0.w);
    o[4] = f2bf(v1.x); o[5] = f2bf(v1.y); o[6] = f2bf(v1.z); o[7] = f2bf(v1.w);
    *(bf16x8*)(Bg + ((size_t)g * K_CODES + k) * 8) = *(bf16x8*)o;
    float s = v0.x * v0.x + v0.y * v0.y + v0.z * v0.z + v0.w * v0.w
            + v1.x * v1.x + v1.y * v1.y + v1.z * v1.z + v1.w * v1.w;
#pragma unroll
    for (int off = 16; off >= 1; off >>= 1) s += __shfl_xor(s, off);
    if ((threadIdx.x & 31) == 0) enorm[k] = s;
    if (gi == 0) { ctrl->done = 0u; ctrl->lsum = 0ull; }
}

// ---------------- K2: everything else ----------------
// grid 256 x 512 thr. Block (b,q): rows n0 = bid*64. Waves: 1m x 8n (wn = wave id).
__global__ __launch_bounds__(512, 2) void vq_main(
        const float* __restrict__ z, const float* __restrict__ emb,
        const ushort_t* __restrict__ Bg, const float* __restrict__ enorm,
        float* __restrict__ out, float* __restrict__ loss, Ctrl* __restrict__ ctrl) {
    __shared__ __align__(16) char smem[138752];
    ushort_t* As  = (ushort_t*)smem;               // [32][64][8] bf16, 32 KB (permanent)
    ushort_t* Bs  = (ushort_t*)(smem + 32768);     // 2 x [2][1024][8] bf16, 64 KB (K loop)
    float*    et  = (float*)(smem + 32768);        // [64][260] f32, 66.5 KB (epilogue, alias Bs)
    float*    zt  = (float*)(smem + 99328);        // [128][68] f32, 34.8 KB (prologue)
    u64*      pmin = (u64*)(smem + 134144);        // [64][8], 4 KB (epilogue)
    float*    znp = (float*)(smem + 134144);       // [8][64] f32 (prologue, alias pmin)
    float*    znL = (float*)(smem + 138240);       // [64] f32
    int*      idxL = (int*)(smem + 138496);        // [64] i32

    const int bid = blockIdx.x, tid = threadIdx.x;
    const int b = bid >> 4, q = bid & 15;
    const int wn = tid >> 6, l = tid & 63;
    const int lane31 = l & 31, hi = l >> 5;

    auto stageB = [&](int buf, int t) {
#pragma unroll
        for (int qq = 0; qq < 4; ++qq) {
            int g = qq * 512 + tid;               // [0,2048)
            int lp = g >> 10, k = g & 1023;
            gload_lds16(Bg + ((size_t)(t * 2 + lp) * K_CODES + k) * 8,
                        Bs + (size_t)buf * 16384 + (size_t)g * 8);
        }
    };

    stageB(0, 0);   // chunk 0 in flight under the whole prologue

    // ---- prologue: z[b][:, q*64..+64) -> As granule-planar bf16 + znorm ----
    const float* zb = z + (size_t)b * (D_DIM * 1024) + q * 64;
    float zn = 0.f;
#pragma unroll
    for (int p = 0; p < 2; ++p) {
#pragma unroll
        for (int i = 0; i < 4; ++i) {
            const int dl = i * 32 + (tid >> 4);
            const int c = (tid & 15) * 4;
            *(float4*)(zt + dl * 68 + c) =
                *(const float4*)(zb + (size_t)(p * 128 + dl) * 1024 + c);
        }
        __syncthreads();
#pragma unroll
        for (int i2 = 0; i2 < 2; ++i2) {
            const int dl = (tid >> 6) * 16 + i2 * 8;   // [0,128)
            float v[8]; ushort_t o[8];
#pragma unroll
            for (int j = 0; j < 8; ++j) {
                v[j] = zt[(dl + j) * 68 + (tid & 63)];
                zn += v[j] * v[j];
                o[j] = f2bf(v[j]);
            }
            *(bf16x8*)(As + ((size_t)((p * 128 + dl) >> 3) * 64 + (tid & 63)) * 8) =
                *(bf16x8*)o;
        }
        __syncthreads();
    }
    znp[(tid >> 6) * 64 + (tid & 63)] = zn;
    __syncthreads();
    if (tid < 64) {
        float s = 0.f;
#pragma unroll
        for (int g = 0; g < 8; ++g) s += znp[g * 64 + tid];
        znL[tid] = s;
    }

    // ---- K loop: 16 chunks of k=16 ----
    f32x16 acc[2][4];
#pragma unroll
    for (int mi = 0; mi < 2; ++mi)
#pragma unroll
        for (int ni = 0; ni < 4; ++ni)
#pragma unroll
            for (int r = 0; r < 16; ++r) acc[mi][ni][r] = 0.f;

    int buf = 0;
    for (int t = 0; t < 16; ++t) {
        if (t < 15) stageB(buf ^ 1, t + 1);
        const ushort_t* Asp = As + ((size_t)(t * 2 + hi) * 64) * 8;
        bf16x8 a0 = *(const bf16x8*)(Asp + (size_t)lane31 * 8);
        bf16x8 a1 = *(const bf16x8*)(Asp + (size_t)(32 + lane31) * 8);
        const ushort_t* Bsp = Bs + (size_t)buf * 16384 + ((size_t)hi * 1024) * 8;
        bf16x8 b0 = *(const bf16x8*)(Bsp + (size_t)(wn * 128 +  0 + lane31) * 8);
        bf16x8 b1 = *(const bf16x8*)(Bsp + (size_t)(wn * 128 + 32 + lane31) * 8);
        bf16x8 b2 = *(const bf16x8*)(Bsp + (size_t)(wn * 128 + 64 + lane31) * 8);
        bf16x8 b3 = *(const bf16x8*)(Bsp + (size_t)(wn * 128 + 96 + lane31) * 8);
        acc[0][0] = __builtin_amdgcn_mfma_f32_32x32x16_bf16(a0, b0, acc[0][0], 0, 0, 0);
        acc[1][0] = __builtin_amdgcn_mfma_f32_32x32x16_bf16(a1, b0, acc[1][0], 0, 0, 0);
        acc[0][1] = __builtin_amdgcn_mfma_f32_32x32x16_bf16(a0, b1, acc[0][1], 0, 0, 0);
        acc[1][1] = __builtin_amdgcn_mfma_f32_32x32x16_bf16(a1, b1, acc[1][1], 0, 0, 0);
        acc[0][2] = __builtin_amdgcn_mfma_f32_32x32x16_bf16(a0, b2, acc[0][2], 0, 0, 0);
        acc[1][2] = __builtin_amdgcn_mfma_f32_32x32x16_bf16(a1, b2, acc[1][2], 0, 0, 0);
        acc[0][3] = __builtin_amdgcn_mfma_f32_32x32x16_bf16(a0, b3, acc[0][3], 0, 0, 0);
        acc[1][3] = __builtin_amdgcn_mfma_f32_32x32x16_bf16(a1, b3, acc[1][3], 0, 0, 0);
        __syncthreads();   // drains next-chunk loads + buffer-reuse fence
        buf ^= 1;
    }

    // ---- epilogue 1: scores, per-wave col-min, cross-wave exchange ----
    float en[4]; unsigned int kg[4];
#pragma unroll
    for (int ni = 0; ni < 4; ++ni) {
        int col = wn * 128 + ni * 32 + lane31;
        en[ni] = enorm[col];
        kg[ni] = (unsigned int)col;
    }
#pragma unroll
    for (int mi = 0; mi < 2; ++mi) {
#pragma unroll
        for (int reg = 0; reg < 16; ++reg) {
            u64 p = ~0ull;
#pragma unroll
            for (int ni = 0; ni < 4; ++ni) {
                float sc = en[ni] - 2.0f * acc[mi][ni][reg];
                unsigned int bb = __float_as_uint(sc);
                unsigned int u = bb ^ (unsigned int)(((int)bb >> 31) | 0x80000000);
                u64 pk = ((u64)u << 32) | kg[ni];
                if (pk < p) p = pk;
            }
#pragma unroll
            for (int off = 16; off >= 1; off >>= 1) {
                u64 qv = __shfl_xor(p, off);
                if (qv < p) p = qv;
            }
            if (lane31 == 0) {
                int row = mi * 32 + (reg & 3) + 8 * (reg >> 2) + 4 * hi;
                pmin[row * 8 + wn] = p;
            }
        }
    }
    __syncthreads();

    // ---- epilogue 2: final per-row min -> idx ; loss partial ----
    if (tid < 64) {
        u64 best = pmin[tid * 8];
#pragma unroll
        for (int i = 1; i < 8; ++i) { u64 qv = pmin[tid * 8 + i]; if (qv < best) best = qv; }
        idxL[tid] = (int)(best & 0xffffffffu);
        unsigned int u = (unsigned int)(best >> 32);
        unsigned int fb = (u & 0x80000000u) ? (u ^ 0x80000000u) : ~u;
        float lp = znL[tid] + __uint_as_float(fb);   // ||z||^2 + (||e||^2 - 2 z.e)
#pragma unroll
        for (int off = 32; off >= 1; off >>= 1) lp += __shfl_xor(lp, off);
        if (tid == 0) {
            u64 fix = (u64)(long long)((double)lp * 1048576.0);
            atomicAdd(&ctrl->lsum, fix);
            __threadfence();
            unsigned old = atomicAdd(&ctrl->done, 1u);
            if (old == 255u) {
                __threadfence();
                u64 tot = atomicAdd(&ctrl->lsum, 0ull);
                loss[0] = (float)((double)tot * (1.25 / (1048576.0 * 4194304.0)));
            }
        }
    }
    __syncthreads();   // idxL ready

    // ---- epilogue 3: gather emb rows -> et[local row m] (padded 260) ----
    // wave w at pass jj reads ONE emb row (m = jj*8+w) fully coalesced (1 KB/wave)
#pragma unroll
    for (int jj = 0; jj < 8; ++jj) {
        int j = jj * 512 + tid;                  // m = j>>6 in [0,64), gr = j&63
        int m = j >> 6, gr = j & 63;
        float4 v = *(const float4*)(emb + (size_t)idxL[m] * D_DIM + gr * 4);
        *(float4*)(et + m * 260 + gr * 4) = v;
    }
    __syncthreads();

    // ---- epilogue 4: out[b][d][q*64 + hw] = et[hw][d]  (LOCAL row index!) ----
    const int hw4 = (tid & 15) * 4;
#pragma unroll
    for (int it = 0; it < 8; ++it) {
        const int d = it * 32 + (tid >> 4);
        float4 qv;
        qv.x = et[(hw4 + 0) * 260 + d];
        qv.y = et[(hw4 + 1) * 260 + d];
        qv.z = et[(hw4 + 2) * 260 + d];
        qv.w = et[(hw4 + 3) * 260 + d];
        *(float4*)(out + ((size_t)(b * 256 + d)) * 1024 + q * 64 + hw4) = qv;
    }
}

extern "C" void kernel_launch(void* const* d_in, const int* in_sizes, int n_in,
                              void* d_out, int out_size, void* d_ws, size_t ws_size,
                              hipStream_t stream) {
    const float* z   = (const float*)d_in[0];
    const float* emb = (const float*)d_in[1];
    float* out  = (float*)d_out;
    float* loss = out + ZQ_SIZE;

    char* ws = (char*)d_ws;
    ushort_t* Bg = (ushort_t*)(ws);           //   524,288 B  [32][1024] 16B granules
    float* enorm = (float*)(ws + 524288);     //     4,096 B
    Ctrl* ctrl   = (Ctrl*)(ws + 528384);      //        16 B

    vq_prep<<<64, 512, 0, stream>>>(emb, Bg, enorm, ctrl);
    vq_main<<<256, 512, 0, stream>>>(z, emb, Bg, enorm, out, loss, ctrl);
}

// Round 10
// 40.920 us; speedup vs baseline: 2.3092x; 1.0942x over previous
//
#include <hip/hip_runtime.h>

// VQ-VAE vector quantizer, MI355X. 2 kernels.
//  K1 vq_prep : emb f32 -> Bg bf16 granule-planar [34][1024][8]; planes 32,33 hold
//               bf16(-enorm/32) replicated (enorm baked into GEMM via ones-chunk);
//               zero ctrl.
//  K2 vq_main : 512 blocks x 256 thr (2 blocks/CU), block = 32 rows x 1024 codes.
//    prologue: z -> As bf16 (direct loads) + f32 znorm -> znG scratch
//    K loop:   17 chunks k=16 (last = enorm chunk w/ A=ones), dbuf staging
//    epilogue: SWAPPED operands => codes in reg-dim => lane-local argmax;
//              1 shfl + tiny LDS combine; gather emb rows -> out; fixed-point loss
// z: [16,256,32,32] f32, emb_w: [1024,256] f32
// out: z_q f32 (4194304) ++ loss scalar (1 float)

#define K_CODES 1024
#define D_DIM   256
#define ZQ_SIZE 4194304
#define NBLK    512

typedef unsigned short ushort_t;
typedef unsigned long long u64;
typedef short bf16x8 __attribute__((ext_vector_type(8)));
typedef float f32x16 __attribute__((ext_vector_type(16)));

struct Ctrl { unsigned done; unsigned pad; u64 lsum; };

__device__ __forceinline__ ushort_t f2bf(float x) {
    unsigned int b = __float_as_uint(x);
    b += 0x7fffu + ((b >> 16) & 1u);   // RNE
    return (ushort_t)(b >> 16);
}

__device__ __forceinline__ void gload_lds16(const void* g, void* l) {
    __builtin_amdgcn_global_load_lds(
        (const __attribute__((address_space(1))) void*)g,
        (__attribute__((address_space(3))) void*)l, 16, 0, 0);
}

// ---------------- K1: emb -> Bg (34 planes) ; zero ctrl ----------------
__global__ __launch_bounds__(512) void vq_prep(
        const float* __restrict__ emb, ushort_t* __restrict__ Bg, Ctrl* __restrict__ ctrl) {
    const int gi = blockIdx.x * 512 + threadIdx.x;   // [0, 32768)
    const int k = gi >> 5, g = gi & 31;
    const float4 v0 = *(const float4*)(emb + k * D_DIM + g * 8);
    const float4 v1 = *(const float4*)(emb + k * D_DIM + g * 8 + 4);
    ushort_t o[8];
    o[0] = f2bf(v0.x); o[1] = f2bf(v0.y); o[2] = f2bf(v0.z); o[3] = f2bf(v0.w);
    o[4] = f2bf(v1.x); o[5] = f2bf(v1.y); o[6] = f2bf(v1.z); o[7] = f2bf(v1.w);
    *(bf16x8*)(Bg + ((size_t)g * K_CODES + k) * 8) = *(bf16x8*)o;
    float s = v0.x * v0.x + v0.y * v0.y + v0.z * v0.z + v0.w * v0.w
            + v1.x * v1.x + v1.y * v1.y + v1.z * v1.z + v1.w * v1.w;
#pragma unroll
    for (int off = 16; off >= 1; off >>= 1) s += __shfl_xor(s, off);   // all 32 lanes get s
    if (g < 2) {   // planes 32,33: replicated bf16(-enorm/32)
        const ushort_t ev = f2bf(s * -0.03125f);
        ushort_t eo[8];
#pragma unroll
        for (int j = 0; j < 8; ++j) eo[j] = ev;
        *(bf16x8*)(Bg + ((size_t)(32 + g) * K_CODES + k) * 8) = *(bf16x8*)eo;
    }
    if (gi == 0) { ctrl->done = 0u; ctrl->lsum = 0ull; }
}

// ---------------- K2: main ----------------
__global__ __launch_bounds__(256, 2) void vq_main(
        const float* __restrict__ z, const float* __restrict__ emb,
        const ushort_t* __restrict__ Bg, float* __restrict__ znG,
        float* __restrict__ out, float* __restrict__ loss, Ctrl* __restrict__ ctrl) {
    __shared__ __align__(16) char smem[81920];           // exactly 160KB/2 per block
    ushort_t* As  = (ushort_t*)smem;                     // [32 planes][32 rows][8], 16 KB
    ushort_t* Bsu = (ushort_t*)(smem + 16384);           // 2 x [2 planes][1024 codes][8], 64 KB
    float* znp    = (float*)(smem + 16384 + 32768);      // [32][4] f32 (aliases Bs buf1, prologue only)
    u64*   pmin   = (u64*)smem;                          // [32][4] (aliases As, epilogue)
    int*   idxL   = (int*)(smem + 1024);                 // [32]    (aliases As, epilogue)
    float* et     = (float*)(smem + 16384);              // [32][260] f32 (aliases Bs, epilogue)

    const int bid = blockIdx.x, tid = threadIdx.x;
    const int b = bid >> 5;
    const int hw0 = (bid & 31) * 32;
    const int w = tid >> 6, l = tid & 63;
    const int lane31 = l & 31, hi = l >> 5;

    auto stage = [&](int sbuf, int t) {
#pragma unroll
        for (int qq = 0; qq < 8; ++qq) {
            int g = qq * 256 + tid;                     // [0,2048) granules
            int lp = g >> 10, kk = g & 1023;
            gload_lds16(Bg + ((size_t)(t * 2 + lp) * K_CODES + kk) * 8,
                        Bsu + (size_t)sbuf * 16384 + (size_t)g * 8);
        }
    };

    stage(0, 0);   // chunk 0 flies under the prologue

    // ---- prologue: z -> As bf16 (direct coalesced loads) + f32 znorm ----
    {
        const float* zb = z + (size_t)b * (D_DIM * 1024) + hw0;
        const int hw = tid & 31, gs = tid >> 5;          // gs in [0,8)
        float zn = 0.f;
#pragma unroll
        for (int gi = 0; gi < 4; ++gi) {
            const int g = gs * 4 + gi;
            float v[8]; ushort_t o[8];
#pragma unroll
            for (int j = 0; j < 8; ++j) v[j] = zb[(size_t)(g * 8 + j) * 1024 + hw];
#pragma unroll
            for (int j = 0; j < 8; ++j) { zn += v[j] * v[j]; o[j] = f2bf(v[j]); }
            *(bf16x8*)(As + ((size_t)g * 32 + hw) * 8) = *(bf16x8*)o;
        }
        zn += __shfl_xor(zn, 32);                        // fold gs pair within wave
        if ((l & 32) == 0) znp[hw * 4 + w] = zn;
        __syncthreads();
        if (tid < 32)
            znG[bid * 32 + tid] = znp[tid * 4] + znp[tid * 4 + 1]
                                + znp[tid * 4 + 2] + znp[tid * 4 + 3];
        __syncthreads();   // znp reads done before t=0 stages into Bs buf1
    }

    // ---- K loop: 16 normal chunks + enorm chunk (dbuf) ----
    f32x16 acc[8];
#pragma unroll
    for (int cf = 0; cf < 8; ++cf)
#pragma unroll
        for (int r = 0; r < 16; ++r) acc[cf][r] = 0.f;

    int buf = 0;
    for (int t = 0; t < 16; ++t) {
        stage(buf ^ 1, t + 1);
        const bf16x8 a = *(const bf16x8*)(As + ((size_t)(t * 2 + hi) * 32 + lane31) * 8);
        const ushort_t* Bb = Bsu + (size_t)buf * 16384 + (size_t)(hi * 1024 + w * 256) * 8;
#pragma unroll
        for (int cf = 0; cf < 8; ++cf) {
            const bf16x8 bf = *(const bf16x8*)(Bb + (size_t)(cf * 32 + lane31) * 8);
            acc[cf] = __builtin_amdgcn_mfma_f32_32x32x16_bf16(bf, a, acc[cf], 0, 0, 0);
        }
        __syncthreads();
        buf ^= 1;
    }
    {   // enorm chunk: A = all-ones (layout-invariant), B = -enorm/32 replicated
        bf16x8 a;
#pragma unroll
        for (int j = 0; j < 8; ++j) a[j] = (short)0x3F80;   // bf16 1.0
        const ushort_t* Bb = Bsu + (size_t)buf * 16384 + (size_t)(hi * 1024 + w * 256) * 8;
#pragma unroll
        for (int cf = 0; cf < 8; ++cf) {
            const bf16x8 bf = *(const bf16x8*)(Bb + (size_t)(cf * 32 + lane31) * 8);
            acc[cf] = __builtin_amdgcn_mfma_f32_32x32x16_bf16(bf, a, acc[cf], 0, 0, 0);
        }
    }

    // ---- epilogue: lane-local argmax over 128 codes (acc = z.e - enorm/2) ----
    {
        float m = acc[0][0];
#pragma unroll
        for (int cf = 0; cf < 8; ++cf)
#pragma unroll
            for (int r = 0; r < 16; ++r) m = fmaxf(m, acc[cf][r]);
        unsigned cc = 0xffffffffu;
#pragma unroll
        for (int cf = 0; cf < 8; ++cf)
#pragma unroll
            for (int r = 0; r < 16; ++r) {
                const unsigned cst = (unsigned)(cf * 32 + (r & 3) + 8 * (r >> 2));
                if (acc[cf][r] == m) cc = cst < cc ? cst : cc;
            }
        unsigned code = cc + (unsigned)(w * 256 + 4 * hi);
        // fold the other hi-half (other 128 codes of this wave's 256)
        const float om = __shfl_xor(m, 32);
        const unsigned oc = __shfl_xor(code, 32);
        if (om > m || (om == m && oc < code)) { m = om; code = oc; }
        // pack sortable-desc key; min key = max score, tie -> min code
        unsigned sb = __float_as_uint(m);
        unsigned s = sb ^ (unsigned)(((int)sb >> 31) | 0x80000000);
        u64 key = ((u64)(~s) << 32) | code;
        if (l < 32) pmin[lane31 * 4 + w] = key;
    }
    __syncthreads();

    // ---- final per-row min across 4 waves -> idx + loss ----
    if (tid < 32) {
        u64 b0 = pmin[tid * 4], b1 = pmin[tid * 4 + 1];
        u64 b2 = pmin[tid * 4 + 2], b3 = pmin[tid * 4 + 3];
        u64 m01 = b0 < b1 ? b0 : b1;
        u64 m23 = b2 < b3 ? b2 : b3;
        u64 best = m01 < m23 ? m01 : m23;
        idxL[tid] = (int)(best & 1023u);
        unsigned us = ~(unsigned)(best >> 32);
        unsigned fb = (us & 0x80000000u) ? (us ^ 0x80000000u) : ~us;
        float sc = __uint_as_float(fb);                 // max(z.e - enorm/2)
        float lp = znG[bid * 32 + tid] - 2.0f * sc;     // ||z||^2 + enorm - 2 z.e
#pragma unroll
        for (int off = 16; off >= 1; off >>= 1) lp += __shfl_xor(lp, off);
        if (tid == 0) {
            u64 fix = (u64)(long long)((double)lp * 1048576.0);
            atomicAdd(&ctrl->lsum, fix);
            __threadfence();
            unsigned old = atomicAdd(&ctrl->done, 1u);
            if (old == (NBLK - 1)) {
                __threadfence();
                u64 tot = atomicAdd(&ctrl->lsum, 0ull);
                loss[0] = (float)((double)tot * (1.25 / (1048576.0 * 4194304.0)));
            }
        }
    }
    __syncthreads();   // idxL ready; Bs reads all done

    // ---- gather emb rows -> et (one row per wave pass, 1 KB coalesced) ----
#pragma unroll
    for (int jj = 0; jj < 8; ++jj) {
        int j = jj * 256 + tid;                  // row = j>>6 in [0,32), gr = j&63
        int mrow = j >> 6, gr = j & 63;
        float4 v = *(const float4*)(emb + (size_t)idxL[mrow] * D_DIM + gr * 4);
        *(float4*)(et + mrow * 260 + gr * 4) = v;
    }
    __syncthreads();

    // ---- out[b][d][hw0+hw] = et[hw][d] ----
    const int hw4 = (tid & 7) * 4;
    const int dr = tid >> 3;                     // 0..31
#pragma unroll
    for (int it = 0; it < 8; ++it) {
        const int d = it * 32 + dr;
        float4 qv;
        qv.x = et[(hw4 + 0) * 260 + d];
        qv.y = et[(hw4 + 1) * 260 + d];
        qv.z = et[(hw4 + 2) * 260 + d];
        qv.w = et[(hw4 + 3) * 260 + d];
        *(float4*)(out + ((size_t)(b * 256 + d)) * 1024 + hw0 + hw4) = qv;
    }
}

extern "C" void kernel_launch(void* const* d_in, const int* in_sizes, int n_in,
                              void* d_out, int out_size, void* d_ws, size_t ws_size,
                              hipStream_t stream) {
    const float* z   = (const float*)d_in[0];
    const float* emb = (const float*)d_in[1];
    float* out  = (float*)d_out;
    float* loss = out + ZQ_SIZE;

    char* ws = (char*)d_ws;
    ushort_t* Bg = (ushort_t*)(ws);           //  557,056 B  [34][1024] 16B granules
    float* znG   = (float*)(ws + 557056);     //   65,536 B  [512][32] f32
    Ctrl* ctrl   = (Ctrl*)(ws + 622592);      //       16 B

    vq_prep<<<64, 512, 0, stream>>>(emb, Bg, ctrl);
    vq_main<<<NBLK, 256, 0, stream>>>(z, emb, Bg, znG, out, loss, ctrl);
}

// Round 11
// 34.755 us; speedup vs baseline: 2.7189x; 1.1774x over previous
//
#include <hip/hip_runtime.h>

// VQ-VAE vector quantizer, MI355X. 2 kernels.
//  K1 vq_prep : emb f32 -> Bg bf16 granule-planar [34][1024][8]; planes 32,33 =
//               bf16(-enorm/32) replicated (enorm baked into GEMM); zero ctrl.
//  K2 vq_main : 256 blocks x 512 thr (1 block/CU), block = 64 rows x 1024 codes.
//    prologue: z -> As bf16 LDS + znorm(LDS); chunks 0,1 staged under it
//    K loop:   17 chunks k=16, 3-buffer ring, counted vmcnt(8/4/0) + raw barriers
//              (never drain prefetch), sched_barrier fence, setprio MFMA cluster
//    epilogue: swapped-operand lane-local argmax -> idx; gather emb -> out;
//              fixed-point u64 loss
// z: [16,256,32,32] f32, emb_w: [1024,256] f32
// out: z_q f32 (4194304) ++ loss scalar (1 float)

#define K_CODES 1024
#define D_DIM   256
#define ZQ_SIZE 4194304
#define NBLK    256

typedef unsigned short ushort_t;
typedef unsigned long long u64;
typedef short bf16x8 __attribute__((ext_vector_type(8)));
typedef float f32x16 __attribute__((ext_vector_type(16)));

struct Ctrl { unsigned done; unsigned pad; u64 lsum; };

__device__ __forceinline__ ushort_t f2bf(float x) {
    unsigned int b = __float_as_uint(x);
    b += 0x7fffu + ((b >> 16) & 1u);   // RNE
    return (ushort_t)(b >> 16);
}

__device__ __forceinline__ void gload_lds16(const void* g, void* l) {
    __builtin_amdgcn_global_load_lds(
        (const __attribute__((address_space(1))) void*)g,
        (__attribute__((address_space(3))) void*)l, 16, 0, 0);
}

// ---------------- K1: emb -> Bg (34 planes) ; zero ctrl ----------------
__global__ __launch_bounds__(512) void vq_prep(
        const float* __restrict__ emb, ushort_t* __restrict__ Bg, Ctrl* __restrict__ ctrl) {
    const int gi = blockIdx.x * 512 + threadIdx.x;   // [0, 32768)
    const int k = gi >> 5, g = gi & 31;
    const float4 v0 = *(const float4*)(emb + k * D_DIM + g * 8);
    const float4 v1 = *(const float4*)(emb + k * D_DIM + g * 8 + 4);
    ushort_t o[8];
    o[0] = f2bf(v0.x); o[1] = f2bf(v0.y); o[2] = f2bf(v0.z); o[3] = f2bf(v0.w);
    o[4] = f2bf(v1.x); o[5] = f2bf(v1.y); o[6] = f2bf(v1.z); o[7] = f2bf(v1.w);
    *(bf16x8*)(Bg + ((size_t)g * K_CODES + k) * 8) = *(bf16x8*)o;
    float s = v0.x * v0.x + v0.y * v0.y + v0.z * v0.z + v0.w * v0.w
            + v1.x * v1.x + v1.y * v1.y + v1.z * v1.z + v1.w * v1.w;
#pragma unroll
    for (int off = 16; off >= 1; off >>= 1) s += __shfl_xor(s, off);   // all 32 lanes
    if (g < 2) {   // planes 32,33: replicated bf16(-enorm/32)
        const ushort_t ev = f2bf(s * -0.03125f);
        ushort_t eo[8];
#pragma unroll
        for (int j = 0; j < 8; ++j) eo[j] = ev;
        *(bf16x8*)(Bg + ((size_t)(32 + g) * K_CODES + k) * 8) = *(bf16x8*)eo;
    }
    if (gi == 0) { ctrl->done = 0u; ctrl->lsum = 0ull; }
}

// ---------------- K2: main ----------------
__global__ __launch_bounds__(512, 2) void vq_main(
        const float* __restrict__ z, const float* __restrict__ emb,
        const ushort_t* __restrict__ Bg,
        float* __restrict__ out, float* __restrict__ loss, Ctrl* __restrict__ ctrl) {
    __shared__ __align__(16) char smem[133632];
    ushort_t* As  = (ushort_t*)smem;                 // [32 planes][64 rows][8], 32 KB
    ushort_t* Bs  = (ushort_t*)(smem + 32768);       // 3 x [2][1024][8], 96 KB ring
    float*    et  = (float*)(smem + 32768);          // [64][260] f32 (epilogue, alias Bs)
    float*    znp = (float*)(smem + 131072);         // [64][8] f32 (prologue)
    u64*      pmin = (u64*)(smem + 131072);          // [64][4]     (epilogue, alias znp)
    float*    znL = (float*)(smem + 133120);         // [64]
    int*      idxL = (int*)(smem + 133376);          // [64]

    const int bid = blockIdx.x, tid = threadIdx.x;
    const int b = bid >> 4;
    const int hw0 = (bid & 15) * 64;
    const int w = tid >> 6, l = tid & 63;
    const int wm = w >> 2, wn = w & 3;               // 2 row-groups x 4 code-groups
    const int lane31 = l & 31, hi = l >> 5;

    auto stage = [&](int sbuf, int t) {
#pragma unroll
        for (int qq = 0; qq < 4; ++qq) {
            int g = qq * 512 + tid;                  // [0,2048) granules
            int lp = g >> 10, kk = g & 1023;
            gload_lds16(Bg + ((size_t)(t * 2 + lp) * K_CODES + kk) * 8,
                        Bs + (size_t)sbuf * 16384 + (size_t)g * 8);
        }
    };

    stage(0, 0);
    stage(1, 1);   // chunks 0,1 fly under the prologue; prologue's own waits drain them

    // ---- prologue: z -> As bf16 (direct coalesced loads) + znorm -> znL ----
    {
        const float* zb = z + (size_t)b * (D_DIM * 1024) + hw0;
        const int hw = tid & 63, gs = tid >> 6;      // gs in [0,8)
        float zn = 0.f;
#pragma unroll
        for (int gi = 0; gi < 4; ++gi) {
            const int g = gs * 4 + gi;               // granule plane [0,32)
            float v[8]; ushort_t o[8];
#pragma unroll
            for (int j = 0; j < 8; ++j) v[j] = zb[(size_t)(g * 8 + j) * 1024 + hw];
#pragma unroll
            for (int j = 0; j < 8; ++j) { zn += v[j] * v[j]; o[j] = f2bf(v[j]); }
            *(bf16x8*)(As + ((size_t)g * 64 + hw) * 8) = *(bf16x8*)o;
        }
        znp[hw * 8 + gs] = zn;
        __syncthreads();                             // As + znp ready; drains stage 0,1
        if (tid < 64) {
            float s = 0.f;
#pragma unroll
            for (int g = 0; g < 8; ++g) s += znp[tid * 8 + g];
            znL[tid] = s;
        }
        __syncthreads();                             // znp reads done; znL ready
    }

    // ---- K loop: 17 chunks (last = enorm), 3-buffer counted-vmcnt pipeline ----
    f32x16 acc[8];
#pragma unroll
    for (int cf = 0; cf < 8; ++cf)
#pragma unroll
        for (int r = 0; r < 16; ++r) acc[cf][r] = 0.f;

#define COMPUTE(BUF, T, ONES) do {                                              \
        const ushort_t* Bp = Bs + (size_t)(BUF) * 16384 +                       \
                             ((size_t)hi * 1024 + wn * 256) * 8;                \
        bf16x8 a;                                                               \
        if (ONES) { _Pragma("unroll")                                           \
            for (int j = 0; j < 8; ++j) a[j] = (short)0x3F80;                   \
        } else {                                                                \
            a = *(const bf16x8*)(As + ((size_t)((T) * 2 + hi) * 64              \
                                       + wm * 32 + lane31) * 8);                \
        }                                                                       \
        __builtin_amdgcn_s_setprio(1);                                          \
        _Pragma("unroll")                                                       \
        for (int cf = 0; cf < 8; ++cf) {                                        \
            const bf16x8 bf = *(const bf16x8*)(Bp + (size_t)(cf * 32 + lane31) * 8); \
            acc[cf] = __builtin_amdgcn_mfma_f32_32x32x16_bf16(bf, a, acc[cf], 0, 0, 0); \
        }                                                                       \
        __builtin_amdgcn_s_setprio(0);                                          \
    } while (0)

    int bcur = 0, bnxt = 2;
    for (int t = 0; t < 15; ++t) {
        stage(bnxt, t + 2);                          // buffer (t+2)%3: last read iter t-1
        asm volatile("s_waitcnt vmcnt(8)" ::: "memory");   // chunk t done; t+1,t+2 in flight
        __builtin_amdgcn_s_barrier();
        __builtin_amdgcn_sched_barrier(0);
        COMPUTE(bcur, t, false);
        __builtin_amdgcn_s_barrier();                // all reads of chunk t done
        bcur = (bcur == 2) ? 0 : bcur + 1;
        bnxt = (bnxt == 2) ? 0 : bnxt + 1;
    }
    // t = 15 (no new stage; chunk 16 still in flight)
    asm volatile("s_waitcnt vmcnt(4)" ::: "memory");
    __builtin_amdgcn_s_barrier();
    __builtin_amdgcn_sched_barrier(0);
    COMPUTE(bcur, 15, false);
    __builtin_amdgcn_s_barrier();
    bcur = (bcur == 2) ? 0 : bcur + 1;
    // t = 16: enorm chunk (planes 32,33), A = ones
    asm volatile("s_waitcnt vmcnt(0)" ::: "memory");
    __builtin_amdgcn_s_barrier();
    __builtin_amdgcn_sched_barrier(0);
    COMPUTE(bcur, 16, true);
#undef COMPUTE

    // ---- epilogue: lane-local argmax over 128 codes (acc = z.e - enorm/2) ----
    {
        float m = acc[0][0];
#pragma unroll
        for (int cf = 0; cf < 8; ++cf)
#pragma unroll
            for (int r = 0; r < 16; ++r) m = fmaxf(m, acc[cf][r]);
        unsigned cc = 0xffffffffu;
#pragma unroll
        for (int cf = 0; cf < 8; ++cf)
#pragma unroll
            for (int r = 0; r < 16; ++r) {
                const unsigned cst = (unsigned)(cf * 32 + (r & 3) + 8 * (r >> 2));
                if (acc[cf][r] == m) cc = cst < cc ? cst : cc;
            }
        unsigned code = cc + (unsigned)(wn * 256 + 4 * hi);
        const float om = __shfl_xor(m, 32);
        const unsigned oc = __shfl_xor(code, 32);
        if (om > m || (om == m && oc < code)) { m = om; code = oc; }
        unsigned sb = __float_as_uint(m);
        unsigned s = sb ^ (unsigned)(((int)sb >> 31) | 0x80000000);
        u64 key = ((u64)(~s) << 32) | code;          // min key = max score, tie->min code
        __builtin_amdgcn_s_barrier();                // As/acc phase done (pmin aliases znp)
        if (l < 32) pmin[(wm * 32 + lane31) * 4 + wn] = key;
    }
    __syncthreads();

    // ---- final per-row min across 4 code-waves -> idx + loss ----
    if (tid < 64) {
        u64 b0 = pmin[tid * 4], b1 = pmin[tid * 4 + 1];
        u64 b2 = pmin[tid * 4 + 2], b3 = pmin[tid * 4 + 3];
        u64 m01 = b0 < b1 ? b0 : b1;
        u64 m23 = b2 < b3 ? b2 : b3;
        u64 best = m01 < m23 ? m01 : m23;
        idxL[tid] = (int)(best & 1023u);
        unsigned us = ~(unsigned)(best >> 32);
        unsigned fb = (us & 0x80000000u) ? (us ^ 0x80000000u) : ~us;
        float sc = __uint_as_float(fb);              // max(z.e - enorm/2)
        float lp = znL[tid] - 2.0f * sc;             // ||z||^2 + enorm - 2 z.e
#pragma unroll
        for (int off = 32; off >= 1; off >>= 1) lp += __shfl_xor(lp, off);
        if (tid == 0) {
            u64 fix = (u64)(long long)((double)lp * 1048576.0);
            atomicAdd(&ctrl->lsum, fix);
            __threadfence();
            unsigned old = atomicAdd(&ctrl->done, 1u);
            if (old == (NBLK - 1)) {
                __threadfence();
                u64 tot = atomicAdd(&ctrl->lsum, 0ull);
                loss[0] = (float)((double)tot * (1.25 / (1048576.0 * 4194304.0)));
            }
        }
    }
    __syncthreads();   // idxL ready; Bs reads all done -> et may overwrite

    // ---- gather emb rows -> et[local row] (1 KB coalesced per wave pass) ----
#pragma unroll
    for (int jj = 0; jj < 8; ++jj) {
        int j = jj * 512 + tid;                      // row = j>>6 in [0,64), gr = j&63
        int mrow = j >> 6, gr = j & 63;
        float4 v = *(const float4*)(emb + (size_t)idxL[mrow] * D_DIM + gr * 4);
        *(float4*)(et + mrow * 260 + gr * 4) = v;
    }
    __syncthreads();

    // ---- out[b][d][hw0+hw] = et[hw][d] ----
    const int hw4 = (tid & 15) * 4;
    const int dr = tid >> 4;                         // 0..31
#pragma unroll
    for (int it = 0; it < 8; ++it) {
        const int d = it * 32 + dr;
        float4 qv;
        qv.x = et[(hw4 + 0) * 260 + d];
        qv.y = et[(hw4 + 1) * 260 + d];
        qv.z = et[(hw4 + 2) * 260 + d];
        qv.w = et[(hw4 + 3) * 260 + d];
        *(float4*)(out + ((size_t)(b * 256 + d)) * 1024 + hw0 + hw4) = qv;
    }
}

extern "C" void kernel_launch(void* const* d_in, const int* in_sizes, int n_in,
                              void* d_out, int out_size, void* d_ws, size_t ws_size,
                              hipStream_t stream) {
    const float* z   = (const float*)d_in[0];
    const float* emb = (const float*)d_in[1];
    float* out  = (float*)d_out;
    float* loss = out + ZQ_SIZE;

    char* ws = (char*)d_ws;
    ushort_t* Bg = (ushort_t*)(ws);           //  557,056 B  [34][1024] 16B granules
    Ctrl* ctrl   = (Ctrl*)(ws + 557056);      //       16 B

    vq_prep<<<64, 512, 0, stream>>>(emb, Bg, ctrl);
    vq_main<<<NBLK, 512, 0, stream>>>(z, emb, Bg, out, loss, ctrl);
}